// Round 12
// baseline (388.503 us; speedup 1.0000x reference)
//
#include <hip/hip_runtime.h>
#include <cmath>

#define CC 21
#define HH 512
#define WW 512
#define HWSZ (HH*WW)
#define CHW (CC*HWSZ)
#define NITERS 5
#define ROWF (CC*WW)          // 10752 elems per image row in HWC
#define TSTR 144              // tile shorts per row; interior at j=8 (16B-aligned)

struct K9 { float k[9]; };

__device__ __forceinline__ float bf16_to_f(unsigned short v) {
    union { unsigned int i; float f; } cv; cv.i = ((unsigned int)v) << 16; return cv.f;
}
__device__ __forceinline__ unsigned short f_to_bf16(float f) {
    union { float f; unsigned int i; } cv; cv.f = f;
    unsigned int b = cv.i + 0x7FFFu + ((cv.i >> 16) & 1u);   // RNE
    return (unsigned short)(b >> 16);
}
__device__ __forceinline__ float lo_bf(unsigned int u) {
    union { unsigned int i; float f; } cv; cv.i = u << 16; return cv.f;
}
__device__ __forceinline__ float hi_bf(unsigned int u) {
    union { unsigned int i; float f; } cv; cv.i = u & 0xFFFF0000u; return cv.f;
}
__device__ __forceinline__ unsigned int pack2_bf(float a, float b) {
    return (unsigned int)f_to_bf16(a) | ((unsigned int)f_to_bf16(b) << 16);
}

// one-time: unaries (HWC fp32) -> bf16
__global__ void convert_u16_kernel(const float* __restrict__ u, unsigned short* __restrict__ u16) {
    size_t i = ((size_t)blockIdx.x*256 + threadIdx.x) * 4;
    float4 f = *(const float4*)(u + i);
    ushort4 o;
    o.x = f_to_bf16(f.x); o.y = f_to_bf16(f.y);
    o.z = f_to_bf16(f.z); o.w = f_to_bf16(f.w);
    *(ushort4*)(u16 + i) = o;
}

// spT[h*W + w] = sp_map[w*W + h]
__global__ void transpose_sp_kernel(const int* __restrict__ sp, int* __restrict__ spT) {
    int p = blockIdx.x*256 + threadIdx.x;
    int h = p >> 9, w = p & (WW - 1);
    spT[p] = sp[w*WW + h];
}

// M = CM @ (SKW + BKW)
__global__ void precomp_M_kernel(const float* __restrict__ skw, const float* __restrict__ bkw,
                                 const float* __restrict__ cm, float* __restrict__ M) {
    int i = blockIdx.x * blockDim.x + threadIdx.x;
    if (i >= CC*CC) return;
    int r = i / CC, k = i - r*CC;
    float a = 0.f;
    for (int j = 0; j < CC; ++j) a += cm[r*CC + j] * (skw[j*CC + k] + bkw[j*CC + k]);
    M[i] = a;
}

// iter-0: sm0 = softmax(u) -> sm16 (+ fp32 smf & redacc slot-0 atomics at clique-0 px)
__launch_bounds__(256)
__global__ void init_sm_kernel(const float* __restrict__ unaries,
                               unsigned short* __restrict__ sm16,
                               float* __restrict__ smf,
                               const int* __restrict__ spT,
                               const int* __restrict__ sp_indices,
                               float* __restrict__ redacc) {
    __shared__ __align__(16) float lu[CC*256];
    __shared__ float acc[44];
    __shared__ int anyC;
    int bid = blockIdx.x;
    int h = bid >> 1, w0 = (bid & 1) << 8;
    int tx = threadIdx.x;
    if (tx < 44) acc[tx] = 0.f;
    if (tx == 0) anyC = 0;
    {
        const float4* src = (const float4*)(unaries + (size_t)h*ROWF + w0*CC);
        float4* dst = (float4*)lu;
        #pragma unroll
        for (int j = 0; j < 6; ++j) {
            int idx = j*256 + tx;
            if (idx < CC*256/4) dst[idx] = src[idx];
        }
    }
    __syncthreads();
    int p = h*WW + w0 + tx;
    float v[CC]; float m = -1e30f;
    #pragma unroll
    for (int c = 0; c < CC; ++c) { v[c] = lu[tx*CC + c]; m = fmaxf(m, v[c]); }
    float s = 0.f;
    #pragma unroll
    for (int c = 0; c < CC; ++c) { v[c] = expf(v[c] - m); s += v[c]; }
    float inv = 1.f / s;
    #pragma unroll
    for (int c = 0; c < CC; ++c) { v[c] *= inv; sm16[(size_t)c*HWSZ + p] = f_to_bf16(v[c]); }

    int idx = sp_indices[0];
    int lab = spT[p];
    if (lab == idx || lab == idx + 1) {
        int mk = (lab == idx) ? 0 : 1;
        anyC = 1;
        atomicAdd(&acc[42 + mk], 1.f);
        for (int c = 0; c < CC; ++c) {
            smf[(size_t)c*HWSZ + p] = v[c];
            atomicAdd(&acc[mk*21 + c], expf(v[c]));
        }
    }
    __syncthreads();
    if (anyC && tx < 44) atomicAdd(&redacc[tx], acc[tx]);
}

// vertical 9-tap blur on bf16, zero pad; 8 pixels/thread (uint4 = 8 bf16).
__launch_bounds__(256)
__global__ void vblur_kernel(const unsigned short* __restrict__ sm16,
                             unsigned short* __restrict__ tmp16, K9 kk) {
    size_t idx = ((size_t)blockIdx.x*256 + threadIdx.x) * 8;
    int p = (int)(idx & (HWSZ - 1));
    int h = p >> 9;
    float a0=0,a1=0,a2=0,a3=0,a4=0,a5=0,a6=0,a7=0;
    const unsigned short* base = sm16 + idx;
    #pragma unroll
    for (int t = 0; t < 9; ++t) {
        int hh = h + t - 4;
        if (hh >= 0 && hh < HH) {
            uint4 v = *(const uint4*)(base + (t - 4)*WW);
            float kt = kk.k[t];
            a0 += kt*lo_bf(v.x); a1 += kt*hi_bf(v.x);
            a2 += kt*lo_bf(v.y); a3 += kt*hi_bf(v.y);
            a4 += kt*lo_bf(v.z); a5 += kt*hi_bf(v.z);
            a6 += kt*lo_bf(v.w); a7 += kt*hi_bf(v.w);
        }
    }
    uint4 o;
    o.x = pack2_bf(a0,a1); o.y = pack2_bf(a2,a3);
    o.z = pack2_bf(a4,a5); o.w = pack2_bf(a6,a7);
    *(uint4*)(tmp16 + idx) = o;
}

// Channel-split fused kernel: 128-px strip per block, 2 threads/pixel
// (half 0: c 0..10, half 1: c 11..20). hblur -> bls (LDS) -> per-thread b pull
// -> M-mix own channels -> clique fixup -> cross-half softmax via pm/ps ->
// sm16/smf/redacc. B computed inline from redacc slot 'iter'.
__launch_bounds__(256)
__global__ void final_kernel(const unsigned short* __restrict__ tmp16,
                             unsigned short* __restrict__ sm16,
                             float* __restrict__ smf,
                             float* __restrict__ outHWC,
                             const unsigned short* __restrict__ u16,
                             const int* __restrict__ spT,
                             const int* __restrict__ sp_indices, int iter,
                             const float* __restrict__ Mg,
                             const float* __restrict__ lwg, const float* __restrict__ hwg,
                             K9 kk, float* __restrict__ redacc, int last) {
    __shared__ __align__(16) unsigned short tileA[CC*TSTR];   // 6048 B
    __shared__ __align__(16) float bls[CC*128];               // 10752 B
    __shared__ float Bsh[42];
    __shared__ float acc[44];
    __shared__ int anyC;
    float* pm = (float*)tileA;          // [256] alias (tileA dead after hblur barrier)
    float* ps = pm + 256;               // [256]

    int bid = blockIdx.x;                      // 0..2047
    int xcd = bid & 7, tt = bid >> 3;          // 256 blocks per XCD chunk
    int h  = xcd*64 + (tt >> 2);
    int w0 = (tt & 3) << 7;                    // quarter-row origin
    int tx = threadIdx.x;
    int px = tx & 127, half = tx >> 7;         // half is wave-uniform

    if (tx < 44) acc[tx] = 0.f;
    if (tx == 0) anyC = 0;
    {   // inline B from previous iteration's partial sums
        const float* rc = redacc + iter*64;
        if (tx < 42) {
            float s = rc[tx], n = rc[42 + tx/21];
            Bsh[tx] = logf((float)HWSZ - n + s);
        }
    }

    // stage vblur'd tile: interior as uint4 (21ch x 16 quads), then halo
    {
        const unsigned short* trow = tmp16 + (size_t)h*WW + w0;
        #pragma unroll
        for (int i = 0; i < 2; ++i) {
            int task = i*256 + tx;
            if (task < CC*16) {
                int c = task >> 4, q = task & 15;
                *(uint4*)(tileA + c*TSTR + 8 + q*8) =
                    *(const uint4*)(trow + (size_t)c*HWSZ + q*8);
            }
        }
        if (tx < CC*8) {
            int c = tx >> 3, k8 = tx & 7;
            int j = (k8 < 4) ? (4 + k8) : (136 + k8 - 4);
            int gw = w0 + j - 8;
            tileA[c*TSTR + j] = (gw >= 0 && gw < WW)
                ? tmp16[(size_t)c*HWSZ + h*WW + gw] : (unsigned short)0;
        }
    }
    __syncthreads();

    int w = w0 + px;
    int p = h*WW + w;
    int CB = half * 11;
    int CN = 11 - half;                        // 11 or 10

    // hblur for own channels -> bls
    #pragma unroll
    for (int i = 0; i < 11; ++i) if (i < CN) {
        int c = CB + i;
        float a = 0.f;
        #pragma unroll
        for (int t = 0; t < 9; ++t)
            a += kk.k[t] * bf16_to_f(tileA[c*TSTR + px + 4 + t]);
        bls[c*128 + px] = a;
    }
    __syncthreads();                           // bls ready; tileA dead

    // pull the full b vector
    float b[CC];
    #pragma unroll
    for (int k = 0; k < CC; ++k) b[k] = bls[k*128 + px];

    // separable norm = s(h)*s(w)
    float sv = 0.f, swn = 0.f;
    #pragma unroll
    for (int t = 0; t < 9; ++t) {
        int hh = h + t - 4; if (hh >= 0 && hh < HH) sv  += kk.k[t];
        int wi = w + t - 4; if (wi >= 0 && wi < WW) swn += kk.k[t];
    }
    float invnorm = 1.f / (sv * swn);

    int idxv = sp_indices[iter];
    int lab  = spT[p];
    bool in1 = (lab == idxv), in2 = (lab == idxv + 1);
    bool incur = in1 | in2;
    float hw0 = hwg[0], hw1 = hwg[1];
    float attc = hw0 + hw1;

    // M-mix for own channels (all qv indices compile-time)
    float qv[11];
    #pragma unroll
    for (int i = 0; i < 11; ++i) if (i < CN) {
        int c = CB + i;
        float pw = 0.f;
        #pragma unroll
        for (int k = 0; k < CC; ++k) pw += Mg[c*CC + k] * b[k];
        qv[i] = bf16_to_f(u16[(size_t)p*CC + c]) - pw*invnorm - attc;
    }
    // rare clique fixup
    if (incur) {
        #pragma unroll
        for (int i = 0; i < 11; ++i) if (i < CN) {
            int c = CB + i;
            float smv = smf[(size_t)c*HWSZ + p];
            float qm  = (smv == 0.f) ? 1.f : smv;
            float ft1 = in1 ? Bsh[c]      / qm : 0.f;
            float ft2 = in2 ? Bsh[CC + c] / qm : 0.f;
            float fta = ft1 + ft2;
            float att = lwg[c]*ft1 + hw0*(1.f - ft1) + lwg[CC + c]*fta + hw1*(1.f - fta);
            qv[i] += attc - att;
        }
    }

    if (!last) {
        // cross-half softmax
        float pml = -1e30f;
        #pragma unroll
        for (int i = 0; i < 11; ++i) if (i < CN) pml = fmaxf(pml, qv[i]);
        pm[tx] = pml;
        __syncthreads();
        float qmax = fmaxf(pm[px], pm[128 + px]);
        float ssl = 0.f;
        #pragma unroll
        for (int i = 0; i < 11; ++i) if (i < CN) {
            float e = expf(qv[i] - qmax);
            qv[i] = e; ssl += e;
        }
        ps[tx] = ssl;
        __syncthreads();
        float inv = 1.f / (ps[px] + ps[128 + px]);

        int idx2 = sp_indices[iter + 1];
        bool n1 = (lab == idx2), n2 = (lab == idx2 + 1);
        bool innext = n1 | n2;
        int mk = n1 ? 0 : 1;
        if (innext && half == 0) { anyC = 1; atomicAdd(&acc[42 + mk], 1.f); }
        #pragma unroll
        for (int i = 0; i < 11; ++i) if (i < CN) {
            int c = CB + i;
            float smv = qv[i] * inv;
            sm16[(size_t)c*HWSZ + p] = f_to_bf16(smv);
            if (innext) {
                smf[(size_t)c*HWSZ + p] = smv;
                atomicAdd(&acc[mk*21 + c], expf(smv));
            }
        }
        __syncthreads();
        if (anyC && tx < 44) atomicAdd(&redacc[(iter+1)*64 + tx], acc[tx]);
    } else {
        // q5 -> out HWC: stage qv into bls (dead), then coalesced float4 gather
        __syncthreads();                       // all b pulls complete
        #pragma unroll
        for (int i = 0; i < 11; ++i) if (i < CN) bls[(CB+i)*128 + px] = qv[i];
        __syncthreads();
        float4* dst = (float4*)(outHWC + (size_t)h*ROWF + (size_t)w0*CC);
        #pragma unroll
        for (int i = 0; i < 3; ++i) {
            int idx = i*256 + tx;
            if (idx < 672) {
                int e = idx * 4;               // e = pix*CC + c
                float4 o;
                o.x = bls[(e       % CC)*128 + (e       / CC)];
                o.y = bls[((e + 1) % CC)*128 + ((e + 1) / CC)];
                o.z = bls[((e + 2) % CC)*128 + ((e + 2) / CC)];
                o.w = bls[((e + 3) % CC)*128 + ((e + 3) / CC)];
                dst[idx] = o;
            }
        }
    }
}

extern "C" void kernel_launch(void* const* d_in, const int* in_sizes, int n_in,
                              void* d_out, int out_size, void* d_ws, size_t ws_size,
                              hipStream_t stream) {
    const float* unaries    = (const float*)d_in[0];
    // d_in[1] = rgb (unused by the reference)
    const int*   sp_map     = (const int*)d_in[2];
    const int*   sp_indices = (const int*)d_in[3];
    const float* skw        = (const float*)d_in[4];
    const float* bkw        = (const float*)d_in[5];
    const float* cm         = (const float*)d_in[6];
    const float* lw         = (const float*)d_in[7];
    const float* hwt        = (const float*)d_in[8];
    float* out = (float*)d_out;

    char* wsb = (char*)d_ws;
    unsigned short* sm16  = (unsigned short*)wsb;                // CHW bf16
    unsigned short* tmp16 = sm16 + CHW;                          // CHW bf16
    unsigned short* u16   = tmp16 + CHW;                         // CHW bf16
    float* smf  = (float*)(u16 + CHW);                           // CHW fp32 (sparse use)
    float* M    = smf + CHW;                                     // 441
    float* redacc = M + CC*CC;                                   // 6 slots x 64
    int*   spT  = (int*)(redacc + 6*64);                         // HWSZ ints

    // 9-tap normalized Gaussian, sigma=3 (fp32, matches reference)
    K9 kk;
    {
        float s = 0.f;
        for (int t = 0; t < 9; ++t) {
            float x = (float)(t - 4) / 3.0f;
            kk.k[t] = expf(-0.5f * x * x);
            s += kk.k[t];
        }
        for (int t = 0; t < 9; ++t) kk.k[t] /= s;
    }

    hipMemsetAsync(redacc, 0, 6*64*sizeof(float), stream);
    convert_u16_kernel<<<CHW/1024, 256, 0, stream>>>(unaries, u16);
    transpose_sp_kernel<<<HWSZ/256, 256, 0, stream>>>(sp_map, spT);
    precomp_M_kernel<<<2, 256, 0, stream>>>(skw, bkw, cm, M);
    init_sm_kernel<<<1024, 256, 0, stream>>>(unaries, sm16, smf, spT, sp_indices, redacc);

    for (int it = 0; it < NITERS; ++it) {
        vblur_kernel<<<CHW/2048, 256, 0, stream>>>(sm16, tmp16, kk);  // sm_it -> tmp
        int last = (it == NITERS - 1);
        final_kernel<<<2048, 256, 0, stream>>>(tmp16, sm16, smf, out, u16, spT,
                                               sp_indices, it, M, lw, hwt,
                                               kk, redacc, last);
    }
}

// Round 13
// 289.177 us; speedup vs baseline: 1.3435x; 1.3435x over previous
//
#include <hip/hip_runtime.h>
#include <cmath>

#define CC 21
#define HH 512
#define WW 512
#define HWSZ (HH*WW)
#define CHW (CC*HWSZ)
#define NITERS 5
#define ROWF (CC*WW)          // 10752 elems per image row in HWC

struct K9 { float k[9]; };

__device__ __forceinline__ float bf16_to_f(unsigned short v) {
    union { unsigned int i; float f; } cv; cv.i = ((unsigned int)v) << 16; return cv.f;
}
__device__ __forceinline__ unsigned short f_to_bf16(float f) {
    union { float f; unsigned int i; } cv; cv.f = f;
    unsigned int b = cv.i + 0x7FFFu + ((cv.i >> 16) & 1u);   // RNE
    return (unsigned short)(b >> 16);
}
__device__ __forceinline__ float lo_bf(unsigned int u) {
    union { unsigned int i; float f; } cv; cv.i = u << 16; return cv.f;
}
__device__ __forceinline__ float hi_bf(unsigned int u) {
    union { unsigned int i; float f; } cv; cv.i = u & 0xFFFF0000u; return cv.f;
}
__device__ __forceinline__ unsigned int pack2_bf(float a, float b) {
    return (unsigned int)f_to_bf16(a) | ((unsigned int)f_to_bf16(b) << 16);
}

// one-time: unaries (HWC fp32) -> bf16
__global__ void convert_u16_kernel(const float* __restrict__ u, unsigned short* __restrict__ u16) {
    size_t i = ((size_t)blockIdx.x*256 + threadIdx.x) * 4;
    float4 f = *(const float4*)(u + i);
    ushort4 o;
    o.x = f_to_bf16(f.x); o.y = f_to_bf16(f.y);
    o.z = f_to_bf16(f.z); o.w = f_to_bf16(f.w);
    *(ushort4*)(u16 + i) = o;
}

// spT[h*W + w] = sp_map[w*W + h]
__global__ void transpose_sp_kernel(const int* __restrict__ sp, int* __restrict__ spT) {
    int p = blockIdx.x*256 + threadIdx.x;
    int h = p >> 9, w = p & (WW - 1);
    spT[p] = sp[w*WW + h];
}

// M = CM @ (SKW + BKW)
__global__ void precomp_M_kernel(const float* __restrict__ skw, const float* __restrict__ bkw,
                                 const float* __restrict__ cm, float* __restrict__ M) {
    int i = blockIdx.x * blockDim.x + threadIdx.x;
    if (i >= CC*CC) return;
    int r = i / CC, k = i - r*CC;
    float a = 0.f;
    for (int j = 0; j < CC; ++j) a += cm[r*CC + j] * (skw[j*CC + k] + bkw[j*CC + k]);
    M[i] = a;
}

// iter-0: sm0 = softmax(u) -> sm16 (+ fp32 smf & redacc slot-0 atomics)
__launch_bounds__(256)
__global__ void init_sm_kernel(const float* __restrict__ unaries,
                               unsigned short* __restrict__ sm16,
                               float* __restrict__ smf,
                               const int* __restrict__ spT,
                               const int* __restrict__ sp_indices,
                               float* __restrict__ redacc) {
    __shared__ __align__(16) float lu[CC*256];
    __shared__ float acc[44];
    __shared__ int anyC;
    int bid = blockIdx.x;
    int h = bid >> 1, w0 = (bid & 1) << 8;
    int tx = threadIdx.x;
    if (tx < 44) acc[tx] = 0.f;
    if (tx == 0) anyC = 0;
    {
        const float4* src = (const float4*)(unaries + (size_t)h*ROWF + w0*CC);
        float4* dst = (float4*)lu;
        #pragma unroll
        for (int j = 0; j < 6; ++j) {
            int idx = j*256 + tx;
            if (idx < CC*256/4) dst[idx] = src[idx];
        }
    }
    __syncthreads();
    int p = h*WW + w0 + tx;
    float v[CC]; float m = -1e30f;
    #pragma unroll
    for (int c = 0; c < CC; ++c) { v[c] = lu[tx*CC + c]; m = fmaxf(m, v[c]); }
    float s = 0.f;
    #pragma unroll
    for (int c = 0; c < CC; ++c) { v[c] = expf(v[c] - m); s += v[c]; }
    float inv = 1.f / s;
    #pragma unroll
    for (int c = 0; c < CC; ++c) { v[c] *= inv; sm16[(size_t)c*HWSZ + p] = f_to_bf16(v[c]); }

    int idx = sp_indices[0];
    int lab = spT[p];
    if (lab == idx || lab == idx + 1) {
        int mk = (lab == idx) ? 0 : 1;
        anyC = 1;
        atomicAdd(&acc[42 + mk], 1.f);
        for (int c = 0; c < CC; ++c) {
            smf[(size_t)c*HWSZ + p] = v[c];
            atomicAdd(&acc[mk*21 + c], expf(v[c]));
        }
    }
    __syncthreads();
    if (anyC && tx < 44) atomicAdd(&redacc[tx], acc[tx]);
}

// FULL separable 9x9 blur (zero pad): sm16 -> mp16. 8 px/thread; vertical taps
// accumulated into a 24-px register window (3 overlapping uint4 loads per tap
// row, L2-cached), then horizontal taps from the window. High TLP: 42 waves/CU.
__launch_bounds__(256)
__global__ void blur_kernel(const unsigned short* __restrict__ sm16,
                            unsigned short* __restrict__ mp16, K9 kk) {
    size_t idx = ((size_t)blockIdx.x*256 + threadIdx.x) * 8;   // (c,h,w0)
    int p  = (int)(idx & (HWSZ - 1));
    int h  = p >> 9;
    int w0 = p & (WW - 1);                                     // multiple of 8
    const unsigned short* rowbase = sm16 + (idx - w0);         // (c,h,0)

    float win[24];
    #pragma unroll
    for (int j = 0; j < 24; ++j) win[j] = 0.f;

    bool hasL = (w0 >= 8), hasR = (w0 <= WW - 16);
    #pragma unroll
    for (int t = 0; t < 9; ++t) {
        int hh = h + t - 4;
        if (hh >= 0 && hh < HH) {
            const unsigned short* r = rowbase + (t - 4)*WW + w0;
            float kt = kk.k[t];
            if (hasL) {
                uint4 v = *(const uint4*)(r - 8);
                win[0] += kt*lo_bf(v.x); win[1] += kt*hi_bf(v.x);
                win[2] += kt*lo_bf(v.y); win[3] += kt*hi_bf(v.y);
                win[4] += kt*lo_bf(v.z); win[5] += kt*hi_bf(v.z);
                win[6] += kt*lo_bf(v.w); win[7] += kt*hi_bf(v.w);
            }
            {
                uint4 v = *(const uint4*)(r);
                win[8]  += kt*lo_bf(v.x); win[9]  += kt*hi_bf(v.x);
                win[10] += kt*lo_bf(v.y); win[11] += kt*hi_bf(v.y);
                win[12] += kt*lo_bf(v.z); win[13] += kt*hi_bf(v.z);
                win[14] += kt*lo_bf(v.w); win[15] += kt*hi_bf(v.w);
            }
            if (hasR) {
                uint4 v = *(const uint4*)(r + 8);
                win[16] += kt*lo_bf(v.x); win[17] += kt*hi_bf(v.x);
                win[18] += kt*lo_bf(v.y); win[19] += kt*hi_bf(v.y);
                win[20] += kt*lo_bf(v.z); win[21] += kt*hi_bf(v.z);
                win[22] += kt*lo_bf(v.w); win[23] += kt*hi_bf(v.w);
            }
        }
    }
    // horizontal: out[j] = sum_t k[t] * win[j + t + 4]
    float o[8];
    #pragma unroll
    for (int j = 0; j < 8; ++j) {
        float a = 0.f;
        #pragma unroll
        for (int t = 0; t < 9; ++t) a += kk.k[t] * win[j + t + 4];
        o[j] = a;
    }
    uint4 ov;
    ov.x = pack2_bf(o[0],o[1]); ov.y = pack2_bf(o[2],o[3]);
    ov.z = pack2_bf(o[4],o[5]); ov.w = pack2_bf(o[6],o[7]);
    *(uint4*)(mp16 + idx) = ov;
}

// final: read blurred field mp16 (coalesced per-channel) -> /norm -> M-mix ->
// clique fixup -> softmax (b[] reuse) -> sm16 + sparse smf/redacc.
// B computed inline from redacc slot 'iter'. No tile staging, no hblur.
__launch_bounds__(256)
__global__ void final_kernel(const unsigned short* __restrict__ mp16,
                             unsigned short* __restrict__ sm16,
                             float* __restrict__ smf,
                             float* __restrict__ outHWC,
                             const unsigned short* __restrict__ u16,
                             const int* __restrict__ spT,
                             const int* __restrict__ sp_indices, int iter,
                             const float* __restrict__ Mg,
                             const float* __restrict__ lwg, const float* __restrict__ hwg,
                             K9 kk, float* __restrict__ redacc, int last) {
    __shared__ __align__(16) float qlds[CC*256];          // 21504 B
    __shared__ __align__(16) unsigned short lu16[CC*256]; // 10752 B
    __shared__ float Bsh[42];
    __shared__ float acc[44];
    __shared__ int anyC;

    int bid = blockIdx.x;                      // 0..1023
    int xcd = bid & 7, tt = bid >> 3;
    int h  = xcd*64 + (tt >> 1);
    int w0 = (tt & 1) << 8;
    int tx = threadIdx.x;

    if (tx < 44) acc[tx] = 0.f;
    if (tx == 0) anyC = 0;
    {   // inline B from accumulated partials of this iteration's clique
        const float* rc = redacc + iter*64;
        if (tx < 42) {
            float s = rc[tx], n = rc[42 + tx/21];
            Bsh[tx] = logf((float)HWSZ - n + s);
        }
    }
    // stage u16 half-row (uint4, 672 quads)
    {
        const uint4* src = (const uint4*)(u16 + (size_t)h*ROWF + w0*CC);
        uint4* dst = (uint4*)lu16;
        #pragma unroll
        for (int j = 0; j < 3; ++j) {
            int idx = j*256 + tx;
            if (idx < CC*256/8) dst[idx] = src[idx];
        }
    }
    __syncthreads();

    int w = w0 + tx;
    int p = h*WW + w;

    // blurred field, coalesced per channel -> the ONLY register array
    float b[CC];
    #pragma unroll
    for (int c = 0; c < CC; ++c) b[c] = bf16_to_f(mp16[(size_t)c*HWSZ + p]);

    // separable norm = s(h)*s(w)
    float sv = 0.f, swn = 0.f;
    #pragma unroll
    for (int t = 0; t < 9; ++t) {
        int hh = h + t - 4; if (hh >= 0 && hh < HH) sv  += kk.k[t];
        int wi = w + t - 4; if (wi >= 0 && wi < WW) swn += kk.k[t];
    }
    float invnorm = 1.f / (sv * swn);

    int idxv = sp_indices[iter];
    int lab  = spT[p];
    bool in1 = (lab == idxv), in2 = (lab == idxv + 1);
    bool incur = in1 | in2;
    float hw0 = hwg[0], hw1 = hwg[1];
    float attc = hw0 + hw1;

    // M-mix (branch-free); qv -> qlds
    float qmax = -1e30f;
    #pragma unroll
    for (int c = 0; c < CC; ++c) {
        float pw = 0.f;
        #pragma unroll
        for (int k = 0; k < CC; ++k) pw += Mg[c*CC + k] * b[k];
        float qv = bf16_to_f(lu16[tx*CC + c]) - pw*invnorm - attc;
        qlds[c*256 + tx] = qv;
        qmax = fmaxf(qmax, qv);
    }
    // rare clique fixup (~650 px total)
    if (incur) {
        qmax = -1e30f;
        for (int c = 0; c < CC; ++c) {
            float smv = smf[(size_t)c*HWSZ + p];
            float qm  = (smv == 0.f) ? 1.f : smv;
            float ft1 = in1 ? Bsh[c]      / qm : 0.f;
            float ft2 = in2 ? Bsh[CC + c] / qm : 0.f;
            float fta = ft1 + ft2;
            float att = lwg[c]*ft1 + hw0*(1.f - ft1) + lwg[CC + c]*fta + hw1*(1.f - fta);
            float qv = qlds[c*256 + tx] + attc - att;
            qlds[c*256 + tx] = qv;
            qmax = fmaxf(qmax, qv);
        }
    }

    if (!last) {
        // softmax: reuse b[] (dead after M-mix)
        float ssum = 0.f;
        #pragma unroll
        for (int c = 0; c < CC; ++c) {
            float e = expf(qlds[c*256 + tx] - qmax);
            b[c] = e; ssum += e;
        }
        float inv = 1.f / ssum;
        #pragma unroll
        for (int c = 0; c < CC; ++c)
            sm16[(size_t)c*HWSZ + p] = f_to_bf16(b[c] * inv);

        int idx2 = sp_indices[iter + 1];
        bool n1 = (lab == idx2), n2 = (lab == idx2 + 1);
        if (n1 | n2) {
            int mk = n1 ? 0 : 1;
            anyC = 1;
            atomicAdd(&acc[42 + mk], 1.f);
            for (int c = 0; c < CC; ++c) {
                float smv = b[c] * inv;
                smf[(size_t)c*HWSZ + p] = smv;
                atomicAdd(&acc[mk*21 + c], expf(smv));
            }
        }
        __syncthreads();
        if (anyC && tx < 44) atomicAdd(&redacc[(iter+1)*64 + tx], acc[tx]);
    } else {
        // q5 -> out HWC: gather float4s directly from qlds, transposed index.
        __syncthreads();
        float4* dst = (float4*)(outHWC + (size_t)h*ROWF + w0*CC);
        #pragma unroll
        for (int j = 0; j < 6; ++j) {
            int idx = j*256 + tx;
            if (idx < CC*256/4) {
                int e = idx * 4;              // e = pix*CC + c
                float4 o;
                o.x = qlds[(e       % CC)*256 + (e       / CC)];
                o.y = qlds[((e + 1) % CC)*256 + ((e + 1) / CC)];
                o.z = qlds[((e + 2) % CC)*256 + ((e + 2) / CC)];
                o.w = qlds[((e + 3) % CC)*256 + ((e + 3) / CC)];
                dst[idx] = o;
            }
        }
    }
}

extern "C" void kernel_launch(void* const* d_in, const int* in_sizes, int n_in,
                              void* d_out, int out_size, void* d_ws, size_t ws_size,
                              hipStream_t stream) {
    const float* unaries    = (const float*)d_in[0];
    // d_in[1] = rgb (unused by the reference)
    const int*   sp_map     = (const int*)d_in[2];
    const int*   sp_indices = (const int*)d_in[3];
    const float* skw        = (const float*)d_in[4];
    const float* bkw        = (const float*)d_in[5];
    const float* cm         = (const float*)d_in[6];
    const float* lw         = (const float*)d_in[7];
    const float* hwt        = (const float*)d_in[8];
    float* out = (float*)d_out;

    char* wsb = (char*)d_ws;
    unsigned short* sm16 = (unsigned short*)wsb;                 // CHW bf16
    unsigned short* mp16 = sm16 + CHW;                           // CHW bf16 (blurred)
    unsigned short* u16  = mp16 + CHW;                           // CHW bf16
    float* smf  = (float*)(u16 + CHW);                           // CHW fp32 (sparse use)
    float* M    = smf + CHW;                                     // 441
    float* redacc = M + CC*CC;                                   // 6 slots x 64
    int*   spT  = (int*)(redacc + 6*64);                         // HWSZ ints

    // 9-tap normalized Gaussian, sigma=3 (fp32, matches reference)
    K9 kk;
    {
        float s = 0.f;
        for (int t = 0; t < 9; ++t) {
            float x = (float)(t - 4) / 3.0f;
            kk.k[t] = expf(-0.5f * x * x);
            s += kk.k[t];
        }
        for (int t = 0; t < 9; ++t) kk.k[t] /= s;
    }

    hipMemsetAsync(redacc, 0, 6*64*sizeof(float), stream);
    convert_u16_kernel<<<CHW/1024, 256, 0, stream>>>(unaries, u16);
    transpose_sp_kernel<<<HWSZ/256, 256, 0, stream>>>(sp_map, spT);
    precomp_M_kernel<<<2, 256, 0, stream>>>(skw, bkw, cm, M);
    init_sm_kernel<<<1024, 256, 0, stream>>>(unaries, sm16, smf, spT, sp_indices, redacc);

    for (int it = 0; it < NITERS; ++it) {
        blur_kernel<<<CHW/2048, 256, 0, stream>>>(sm16, mp16, kk);   // full 9x9 blur
        int last = (it == NITERS - 1);
        final_kernel<<<1024, 256, 0, stream>>>(mp16, sm16, smf, out, u16, spT,
                                               sp_indices, it, M, lw, hwt,
                                               kk, redacc, last);
    }
}